// Round 1
// baseline (286.567 us; speedup 1.0000x reference)
//
#include <hip/hip_runtime.h>
#include <cmath>

#define NB 256
#define NS 8192
#define NF 2048
#define NK 20

typedef _Float16 half8 __attribute__((ext_vector_type(8)));
typedef _Float16 half4 __attribute__((ext_vector_type(4)));
typedef float f32x4 __attribute__((ext_vector_type(4)));

__device__ __forceinline__ void async16(const void* g, void* l) {
  __builtin_amdgcn_global_load_lds(
      (const __attribute__((address_space(1))) unsigned int*)g,
      (__attribute__((address_space(3))) unsigned int*)l, 16, 0, 0);
}

__device__ __forceinline__ float waveSum(float v) {
#pragma unroll
  for (int off = 32; off > 0; off >>= 1) v += __shfl_xor(v, off, 64);
  return v;
}
__device__ __forceinline__ float waveMax(float v) {
#pragma unroll
  for (int off = 32; off > 0; off >>= 1) v = fmaxf(v, __shfl_xor(v, off, 64));
  return v;
}

// ---- copy features -> output region (fp32) and convert to fp16 scratch ----
__global__ __launch_bounds__(256) void prep_features(const float4* __restrict__ f4,
                                                     float* __restrict__ outF,
                                                     _Float16* __restrict__ fh) {
  int idx = blockIdx.x * 256 + threadIdx.x;  // over NS*NF/4 float4 groups
  float4 v = f4[idx];
  int e = idx * 4;
  // out region starts at +3 floats (12B) -> scalar stores (misaligned for vec)
  outF[e + 0] = v.x; outF[e + 1] = v.y; outF[e + 2] = v.z; outF[e + 3] = v.w;
  half4 h;
  h[0] = (_Float16)v.x; h[1] = (_Float16)v.y; h[2] = (_Float16)v.z; h[3] = (_Float16)v.w;
  *(half4*)(fh + e) = h;
}

// ---- x = normalize(inputs0); fp32 + fp16 copies ----
__global__ __launch_bounds__(256) void normalize_x(const float* __restrict__ in0,
                                                   float* __restrict__ xf,
                                                   _Float16* __restrict__ xh) {
  __shared__ float red[4];
  int b = blockIdx.x, tid = threadIdx.x;
  const float4* row = (const float4*)(in0 + (size_t)b * NF);
  float4 v0 = row[tid], v1 = row[tid + 256];
  float ss = v0.x * v0.x + v0.y * v0.y + v0.z * v0.z + v0.w * v0.w +
             v1.x * v1.x + v1.y * v1.y + v1.z * v1.z + v1.w * v1.w;
  float w = waveSum(ss);
  int wave = tid >> 6, lane = tid & 63;
  if (lane == 0) red[wave] = w;
  __syncthreads();
  float tot = (red[0] + red[1]) + (red[2] + red[3]);
  float inv = 1.0f / fmaxf(sqrtf(tot), 1e-12f);
  float4 o0 = make_float4(v0.x * inv, v0.y * inv, v0.z * inv, v0.w * inv);
  float4 o1 = make_float4(v1.x * inv, v1.y * inv, v1.z * inv, v1.w * inv);
  ((float4*)(xf + (size_t)b * NF))[tid] = o0;
  ((float4*)(xf + (size_t)b * NF))[tid + 256] = o1;
  half4 h0, h1;
  h0[0] = (_Float16)o0.x; h0[1] = (_Float16)o0.y; h0[2] = (_Float16)o0.z; h0[3] = (_Float16)o0.w;
  h1[0] = (_Float16)o1.x; h1[1] = (_Float16)o1.y; h1[2] = (_Float16)o1.z; h1[3] = (_Float16)o1.w;
  ((half4*)(xh + (size_t)b * NF))[tid] = h0;
  ((half4*)(xh + (size_t)b * NF))[tid + 256] = h1;
}

// ---- per-row neighbor weights, KL mask weights, scatter winner mask ----
// nbw[b*20+k] = (bits(neighbor), w_ln1, w_kl, 0)
__global__ __launch_bounds__(256) void prep_small(const int* __restrict__ targets,
                                                  const int* __restrict__ neighbors,
                                                  const float* __restrict__ ndist,
                                                  float4* __restrict__ nbw,
                                                  int* __restrict__ winner) {
  int b = threadIdx.x;
  int tg = targets[b];
  int w = 1;
  for (int b2 = b + 1; b2 < NB; ++b2)
    if (targets[b2] == tg) { w = 0; break; }
  winner[b] = w;

  float e[NK];
  float s = 0.0f;
  int cnt = 0;
  for (int k = 0; k < NK; ++k) {
    float d = ndist[b * NK + k];
    e[k] = expf(d * (1.0f / 0.6f));
    s += e[k];
    cnt += (d <= 2.0f) ? 1 : 0;
  }
  float invs = 1.0f / (2.0f * s);              // softmax over 2K duplicated dists
  float invc = 1.0f / fmaxf((float)cnt, 1.0f); // mask count (== K here)
  for (int k = 0; k < NK; ++k) {
    float d = ndist[b * NK + k];
    nbw[b * NK + k] = make_float4(__int_as_float(neighbors[b * NK + k]),
                                  e[k] * invs,
                                  (d <= 2.0f) ? invc : 0.0f, 0.0f);
  }
}

// ---- scores = (x @ features^T) / TEMP via fp16 MFMA, 64x128 tiles ----
__global__ __launch_bounds__(256) void gemm_scores(const _Float16* __restrict__ xh,
                                                   const _Float16* __restrict__ fh,
                                                   float* __restrict__ scores) {
  __shared__ _Float16 As[64 * 32];   // 4 KB
  __shared__ _Float16 Bs[128 * 32];  // 8 KB
  int tid = threadIdx.x;
  int m0 = blockIdx.y * 64;
  int n0 = blockIdx.x * 128;
  int wave = tid >> 6, lane = tid & 63;
  int wm = (wave >> 1) * 32, wn = (wave & 1) * 64;
  int quad = lane >> 4, r16 = lane & 15;
  f32x4 acc[2][4] = {};

  const _Float16* agp = xh + (size_t)(m0 + (tid >> 2)) * NF + (tid & 3) * 8;
  const _Float16* bgp1 = fh + (size_t)(n0 + (tid >> 2)) * NF + (tid & 3) * 8;
  const _Float16* bgp2 = fh + (size_t)(n0 + 64 + (tid >> 2)) * NF + (tid & 3) * 8;

  for (int k0 = 0; k0 < NF; k0 += 32) {
    __syncthreads();
    async16(agp + k0, &As[tid * 8]);
    async16(bgp1 + k0, &Bs[tid * 8]);
    async16(bgp2 + k0, &Bs[(256 + tid) * 8]);
    __syncthreads();
    half8 af[2], bf[4];
#pragma unroll
    for (int i = 0; i < 2; ++i)
      af[i] = *(const half8*)&As[(wm + i * 16 + r16) * 32 + quad * 8];
#pragma unroll
    for (int j = 0; j < 4; ++j)
      bf[j] = *(const half8*)&Bs[(wn + j * 16 + r16) * 32 + quad * 8];
#pragma unroll
    for (int i = 0; i < 2; ++i)
#pragma unroll
      for (int j = 0; j < 4; ++j)
        acc[i][j] = __builtin_amdgcn_mfma_f32_16x16x32_f16(af[i], bf[j], acc[i][j], 0, 0, 0);
  }
#pragma unroll
  for (int i = 0; i < 2; ++i)
#pragma unroll
    for (int j = 0; j < 4; ++j)
#pragma unroll
      for (int r = 0; r < 4; ++r) {
        int M = m0 + wm + i * 16 + quad * 4 + r;
        int N = n0 + wn + j * 16 + r16;
        scores[(size_t)M * NS + N] = acc[i][j][r] * 20.0f;  // 1/TEMP
      }
}

// ---- row max & sumexp for logits0 (rows 0..255) and logits1 (256..511) ----
__global__ __launch_bounds__(256) void row_stats(const float* __restrict__ logits0,
                                                 const float* __restrict__ logits1,
                                                 float* __restrict__ m_all,
                                                 float* __restrict__ l_all) {
  __shared__ float red[4];
  int r = blockIdx.x, tid = threadIdx.x;
  const float* src = (r < NB) ? logits0 : logits1;
  const float4* row = (const float4*)(src + (size_t)(r & (NB - 1)) * NS);
  float4 v[8];
  float mx = -1e30f;
#pragma unroll
  for (int i = 0; i < 8; ++i) {
    v[i] = row[tid + i * 256];
    mx = fmaxf(mx, fmaxf(fmaxf(v[i].x, v[i].y), fmaxf(v[i].z, v[i].w)));
  }
  float wv = waveMax(mx);
  int wave = tid >> 6, lane = tid & 63;
  if (lane == 0) red[wave] = wv;
  __syncthreads();
  float m = fmaxf(fmaxf(red[0], red[1]), fmaxf(red[2], red[3]));
  __syncthreads();
  float se = 0.0f;
#pragma unroll
  for (int i = 0; i < 8; ++i)
    se += expf(v[i].x - m) + expf(v[i].y - m) + expf(v[i].z - m) + expf(v[i].w - m);
  float sw = waveSum(se);
  if (lane == 0) red[wave] = sw;
  __syncthreads();
  float l = (red[0] + red[1]) + (red[2] + red[3]);
  if (tid == 0) { m_all[r] = m; l_all[r] = l; }
}

// ---- loss_nce from scores: -mean(logsoftmax(scores)[b, target_b]) ----
__global__ __launch_bounds__(256) void score_lse(const float* __restrict__ scores,
                                                 const int* __restrict__ targets,
                                                 float* __restrict__ acc) {
  __shared__ float red[4];
  int b = blockIdx.x, tid = threadIdx.x;
  const float4* row = (const float4*)(scores + (size_t)b * NS);
  float4 v[8];
  float mx = -1e30f;
#pragma unroll
  for (int i = 0; i < 8; ++i) {
    v[i] = row[tid + i * 256];
    mx = fmaxf(mx, fmaxf(fmaxf(v[i].x, v[i].y), fmaxf(v[i].z, v[i].w)));
  }
  float wv = waveMax(mx);
  int wave = tid >> 6, lane = tid & 63;
  if (lane == 0) red[wave] = wv;
  __syncthreads();
  float m = fmaxf(fmaxf(red[0], red[1]), fmaxf(red[2], red[3]));
  __syncthreads();
  float se = 0.0f;
#pragma unroll
  for (int i = 0; i < 8; ++i)
    se += expf(v[i].x - m) + expf(v[i].y - m) + expf(v[i].z - m) + expf(v[i].w - m);
  float sw = waveSum(se);
  if (lane == 0) red[wave] = sw;
  __syncthreads();
  float l = (red[0] + red[1]) + (red[2] + red[3]);
  if (tid == 0) {
    float st = scores[(size_t)b * NS + targets[b]];
    atomicAdd(acc + 0, -(st - m - logf(l)));
  }
}

// ---- neighbor mixture losses: CE (w/ onehot) and KL accumulators ----
// LDS holds p0/p1 interleaved for a 32-column tile across all 256 rows.
__global__ __launch_bounds__(256) void neighbor_losses(
    const float* __restrict__ logits0, const float* __restrict__ logits1,
    const float* __restrict__ m_all, const float* __restrict__ l_all,
    const float4* __restrict__ nbw, const int* __restrict__ targets,
    float* __restrict__ acc) {
  __shared__ float2 pq[NB * 32];  // 64 KB exactly
  int tid = threadIdx.x;
  int col0 = blockIdx.x * 32;
  {
    int row = tid;
    float im0 = m_all[row], il0 = 1.0f / l_all[row];
    float im1 = m_all[NB + row], il1 = 1.0f / l_all[NB + row];
    const float4* r0 = (const float4*)(logits0 + (size_t)row * NS + col0);
    const float4* r1 = (const float4*)(logits1 + (size_t)row * NS + col0);
#pragma unroll
    for (int g = 0; g < 8; ++g) {
      float4 a = r0[g], c = r1[g];
      float2* dst = &pq[row * 32 + g * 4];
      dst[0] = make_float2(expf(a.x - im0) * il0, expf(c.x - im1) * il1);
      dst[1] = make_float2(expf(a.y - im0) * il0, expf(c.y - im1) * il1);
      dst[2] = make_float2(expf(a.z - im0) * il0, expf(c.z - im1) * il1);
      dst[3] = make_float2(expf(a.w - im0) * il0, expf(c.w - im1) * il1);
    }
  }
  __syncthreads();
  int wave = tid >> 6, lane = tid & 63, half = lane >> 5, col = lane & 31;
  int gcol = col0 + col;
  float sce = 0.0f, skl = 0.0f;
  for (int it = 0; it < 32; ++it) {
    int b = wave * 64 + it * 2 + half;
    const float4* nb = nbw + b * NK;
    float accl = 0.0f, acck = 0.0f;
#pragma unroll
    for (int k = 0; k < NK; ++k) {
      float4 q = nb[k];
      int n = __float_as_int(q.x);
      float2 p = pq[n * 32 + col];
      accl = fmaf(q.y, p.x + p.y, accl);
      acck = fmaf(q.z, p.x, acck);
    }
    float2 own = pq[b * 32 + col];
    float lp0 = logf(fmaxf(own.x, 1e-37f));
    float lp1 = logf(fmaxf(own.y, 1e-37f));
    float ce = -0.1f * accl * lp0;                 // (1-ALPHA) = 0.1
    if (gcol == targets[b]) ce -= 0.9f * lp0;      // ALPHA = 0.9 onehot term
    float klv = (acck > 0.0f) ? acck * (logf(fmaxf(acck, 1e-12f)) - lp1) : 0.0f;
    sce += ce;
    skl += klv;
  }
  sce = waveSum(sce);
  skl = waveSum(skl);
  if (lane == 0) {
    atomicAdd(acc + 1, sce);
    atomicAdd(acc + 2, skl);
  }
}

// ---- momentum update rows (last-occurrence wins, like np fancy indexing) ----
__global__ __launch_bounds__(256) void scatter_update(const float* __restrict__ features,
                                                      const float* __restrict__ xf,
                                                      const int* __restrict__ targets,
                                                      const int* __restrict__ winner,
                                                      float* __restrict__ outF) {
  __shared__ float red[4];
  int b = blockIdx.x;
  if (!winner[b]) return;
  int t = targets[b];
  int tid = threadIdx.x;
  const float* fr = features + (size_t)t * NF;
  const float* xr = xf + (size_t)b * NF;
  float u[8];
  float ss = 0.0f;
#pragma unroll
  for (int i = 0; i < 8; ++i) {
    int e = tid + i * 256;
    u[i] = 0.2f * fr[e] + 0.8f * xr[e];  // MOMENTUM = 0.2
    ss += u[i] * u[i];
  }
  float wv = waveSum(ss);
  int wave = tid >> 6, lane = tid & 63;
  if (lane == 0) red[wave] = wv;
  __syncthreads();
  float tot = (red[0] + red[1]) + (red[2] + red[3]);
  float inv = 1.0f / fmaxf(sqrtf(tot), 1e-12f);
#pragma unroll
  for (int i = 0; i < 8; ++i)
    outF[(size_t)t * NF + tid + i * 256] = u[i] * inv;
}

__global__ void finalize(const float* __restrict__ acc, const float* __restrict__ rampup,
                         float* __restrict__ out) {
  if (threadIdx.x == 0) {
    out[0] = acc[0] * (1.0f / 256.0f);             // loss_nce
    out[1] = acc[1] * (1.0f / 256.0f);             // LAMBDA1 * loss_ce
    out[2] = rampup[0] * acc[2] * (1.0f / 256.0f); // LAMBDA2 * rampup * kl
  }
}

extern "C" void kernel_launch(void* const* d_in, const int* in_sizes, int n_in,
                              void* d_out, int out_size, void* d_ws, size_t ws_size,
                              hipStream_t stream) {
  const float* inputs0 = (const float*)d_in[0];
  const float* logits0 = (const float*)d_in[1];
  const float* logits1 = (const float*)d_in[2];
  const int* targets = (const int*)d_in[3];
  // d_in[4] = indexes (identity, unused)
  const int* neighbors = (const int*)d_in[5];
  const float* ndist = (const float*)d_in[6];
  const float* rampup = (const float*)d_in[7];
  const float* features = (const float*)d_in[8];
  float* out = (float*)d_out;

  char* ws = (char*)d_ws;
  float* acc = (float*)(ws);                         // 64 B (zeroed)
  int* winner = (int*)(ws + 1024);                   // 1 KB
  float4* nbw = (float4*)(ws + 4096);                // 80 KB
  float* m_all = (float*)(ws + 131072);              // 2 KB
  float* l_all = (float*)(ws + 131072 + 2048);       // 2 KB
  float* xf = (float*)(ws + (1 << 20));              // 2 MB
  _Float16* xh = (_Float16*)(ws + (3 << 20));        // 1 MB
  float* scores = (float*)(ws + (4 << 20));          // 8 MB
  _Float16* fh = (_Float16*)(ws + (12 << 20));       // 32 MB

  hipMemsetAsync(acc, 0, 64, stream);
  prep_features<<<NS * NF / 4 / 256, 256, 0, stream>>>((const float4*)features, out + 3, fh);
  normalize_x<<<NB, 256, 0, stream>>>(inputs0, xf, xh);
  prep_small<<<1, 256, 0, stream>>>(targets, neighbors, ndist, nbw, winner);
  gemm_scores<<<dim3(NS / 128, NB / 64), 256, 0, stream>>>(xh, fh, scores);
  row_stats<<<2 * NB, 256, 0, stream>>>(logits0, logits1, m_all, l_all);
  score_lse<<<NB, 256, 0, stream>>>(scores, targets, acc);
  neighbor_losses<<<NS / 32, 256, 0, stream>>>(logits0, logits1, m_all, l_all, nbw, targets, acc);
  scatter_update<<<NB, 256, 0, stream>>>(features, xf, targets, winner, out + 3);
  finalize<<<1, 64, 0, stream>>>(acc, rampup, out);
}